// Round 2
// baseline (1049.021 us; speedup 1.0000x reference)
//
#include <hip/hip_runtime.h>
#include <hip/hip_bf16.h>

// Network: bidirectional LSTM (T=256, B=1024, E=300, H=50) + small MLP head.
// h_bw[0] needs only ONE backward step (zero init state); x@Wx hoisted into
// per-VOCAB precompute P = E @ W_fw[0:300,:]  (50000 x 200, 40 MB in d_ws).

#define VOCAB 50000
#define EMB   300
#define HID   50
#define GATES 200          // 4*H
#define BATCH 1024
#define TT    256          // 2*MAX_LEN
#define BN_SCALE 0.9995003746877732f   // 1/sqrt(1.001)

__device__ __forceinline__ float sigm(float x) {
    return 1.0f / (1.0f + __expf(-x));
}
__device__ __forceinline__ float tanh_f(float x) {
    // tanh(x) = 1 - 2/(e^{2x}+1); saturates correctly for |x| large
    return 1.0f - 2.0f / (__expf(2.0f * x) + 1.0f);
}

// ---------------------------------------------------------------------------
// K1: P[v][j] = sum_e E[v][e] * Wx[e][j]   (Wx = W_fw rows 0..299)
// No LDS: E-tile addresses are block-uniform -> scalar (s_load) path through
// the K$ pipe; Wx column values are coalesced vector loads reused across 32
// register-blocked vocab rows. VALU-issue-bound by design.
// ---------------------------------------------------------------------------
__global__ __launch_bounds__(256) void vocab_proj(const float* __restrict__ E,
                                                  const float* __restrict__ Wx,
                                                  float* __restrict__ P) {
    const int v0 = blockIdx.x * 32;
    const int t  = threadIdx.x;

    float acc[32];
#pragma unroll
    for (int r = 0; r < 32; ++r) acc[r] = 0.0f;

    if (t < GATES) {
        for (int e = 0; e < EMB; e += 4) {
            const float w0 = Wx[(e + 0) * GATES + t];
            const float w1 = Wx[(e + 1) * GATES + t];
            const float w2 = Wx[(e + 2) * GATES + t];
            const float w3 = Wx[(e + 3) * GATES + t];
#pragma unroll
            for (int r = 0; r < 32; ++r) {
                // uniform address (no threadIdx) -> scalar loads; clamp the
                // tail block's overrun rows (reads only, stores are guarded)
                const int vr = (v0 + r < VOCAB) ? (v0 + r) : (VOCAB - 1);
                const float* Er = E + (size_t)vr * EMB + e;
                acc[r] = fmaf(Er[3], w3, fmaf(Er[2], w2,
                         fmaf(Er[1], w1, fmaf(Er[0], w0, acc[r]))));
            }
        }
#pragma unroll
        for (int r = 0; r < 32; ++r) {
            const int v = v0 + r;
            if (v < VOCAB) P[(size_t)v * GATES + t] = acc[r];
        }
    }
}

// ---------------------------------------------------------------------------
// K2: forward LSTM. ONE WAVE per batch row; lane u (<50) owns hidden unit u
// and all 4 of its gate columns (Whh cols in 200 VGPRs). h broadcast via
// __shfl (constant lane index) -> no LDS traffic, no barriers in the loop.
// Tokens pre-staged to LDS; P rows prefetched at depth 2 (A/B register sets,
// unroll-2 loop) so the L3 gather latency is always ~2 steps in flight.
// ---------------------------------------------------------------------------
#define LSTM_STEP(PI, PJ, PF, PO, TNEXT)                                      \
    {                                                                         \
        float ai = PI + bi0, aj = PJ + bj0, af = PF + bf0, ao = PO + bo0;     \
        {   /* reissue prefetch: row for token at step TNEXT */               \
            const int tk = stok[TNEXT];                                       \
            const float* pr = P + (size_t)tk * GATES + u;                     \
            PI = pr[0]; PJ = pr[50]; PF = pr[100]; PO = pr[150];              \
        }                                                                     \
        _Pragma("unroll")                                                     \
        for (int k = 0; k < HID; ++k) {                                       \
            const float hk = __shfl(h, k);                                    \
            ai = fmaf(wi[k], hk, ai);                                         \
            aj = fmaf(wj[k], hk, aj);                                         \
            af = fmaf(wf[k], hk, af);                                         \
            ao = fmaf(wo[k], hk, ao);                                         \
        }                                                                     \
        c = c * sigm(af + 1.0f) + sigm(ai) * tanh_f(aj);                      \
        h = tanh_f(c) * sigm(ao);                                             \
    }

__global__ __launch_bounds__(64, 1) void lstm_fw(const int* __restrict__ x1,
                                                 const int* __restrict__ x2,
                                                 const float* __restrict__ P,
                                                 const float* __restrict__ Wfw,
                                                 const float* __restrict__ bfw,
                                                 float* __restrict__ feat) {
    const int b = blockIdx.x;
    const int u = threadIdx.x;

    __shared__ int stok[TT];
    // stage all 256 tokens once (removes the per-step token->gather chain)
    for (int i = u; i < 128; i += 64) {
        stok[i]       = x1[b * 128 + i];
        stok[128 + i] = x2[b * 128 + i];
    }
    __syncthreads();   // once, outside the loop

    if (u < HID) {
        float wi[HID], wj[HID], wf[HID], wo[HID];
        const float bi0 = bfw[u];
        const float bj0 = bfw[u + 50];
        const float bf0 = bfw[u + 100];
        const float bo0 = bfw[u + 150];
#pragma unroll
        for (int k = 0; k < HID; ++k) {
            const float* row = Wfw + (size_t)(EMB + k) * GATES;
            wi[k] = row[u];
            wj[k] = row[u + 50];
            wf[k] = row[u + 100];
            wo[k] = row[u + 150];
        }

        float c = 0.0f, h = 0.0f;

        // prologue: rows for steps 0 and 1 in flight
        float pAi, pAj, pAf, pAo, pBi, pBj, pBf, pBo;
        {
            const float* pr = P + (size_t)stok[0] * GATES + u;
            pAi = pr[0]; pAj = pr[50]; pAf = pr[100]; pAo = pr[150];
        }
        {
            const float* pr = P + (size_t)stok[1] * GATES + u;
            pBi = pr[0]; pBj = pr[50]; pBf = pr[100]; pBo = pr[150];
        }

        for (int t = 0; t < TT; t += 2) {
            const int n2 = (t + 2 < TT) ? t + 2 : TT - 1;   // clamp: harmless
            const int n3 = (t + 3 < TT) ? t + 3 : TT - 1;   // dup load at tail
            LSTM_STEP(pAi, pAj, pAf, pAo, n2);
            LSTM_STEP(pBi, pBj, pBf, pBo, n3);
        }

        feat[b * (2 * HID) + u] = h;
    }
}

// ---------------------------------------------------------------------------
// K3: backward LSTM = ONE step (zero init state, h part of W unused), fused
// with BN-scale + MLP head (100 -> 25 -> 3). One block per batch row.
// ---------------------------------------------------------------------------
__global__ __launch_bounds__(256) void bw_mlp(const int* __restrict__ x2,
                                              const float* __restrict__ E,
                                              const float* __restrict__ Wbw,
                                              const float* __restrict__ bbw,
                                              const float* __restrict__ W1,
                                              const float* __restrict__ b1,
                                              const float* __restrict__ W2,
                                              const float* __restrict__ b2,
                                              const float* __restrict__ featfw,
                                              float* __restrict__ out) {
    const int b = blockIdx.x;
    const int t = threadIdx.x;

    __shared__ __align__(16) float sx[EMB + 4];
    __shared__ float sf[2 * HID];
    __shared__ float sg[GATES];
    __shared__ float sh1[25];

    const int tok = x2[b * 128 + 127];   // xs[T-1] token
    for (int e = t; e < EMB; e += 256) sx[e] = E[(size_t)tok * EMB + e];
    if (t < HID) sf[t] = featfw[b * (2 * HID) + t];
    __syncthreads();

    if (t < GATES) {
        float g0 = bbw[t], g1 = 0.0f, g2 = 0.0f, g3 = 0.0f;
        for (int e = 0; e < EMB; e += 4) {
            g0 = fmaf(sx[e + 0], Wbw[(e + 0) * GATES + t], g0);
            g1 = fmaf(sx[e + 1], Wbw[(e + 1) * GATES + t], g1);
            g2 = fmaf(sx[e + 2], Wbw[(e + 2) * GATES + t], g2);
            g3 = fmaf(sx[e + 3], Wbw[(e + 3) * GATES + t], g3);
        }
        sg[t] = (g0 + g1) + (g2 + g3);
    }
    __syncthreads();

    if (t < HID) {
        // c=0: c2 = sigm(i)*tanh(j); h = tanh(c2)*sigm(o)
        const float c2 = sigm(sg[t]) * tanh_f(sg[t + HID]);
        sf[HID + t] = tanh_f(c2) * sigm(sg[t + 3 * HID]);
    }
    __syncthreads();

    if (t < 25) {
        float a = 0.0f;
#pragma unroll 4
        for (int k = 0; k < 2 * HID; ++k)
            a = fmaf(sf[k], W1[k * 25 + t], a);
        a = fmaf(a, BN_SCALE, b1[t]);
        sh1[t] = fmaxf(a, 0.0f);
    }
    __syncthreads();

    if (t < 3) {
        float a = b2[t];
#pragma unroll
        for (int k = 0; k < 25; ++k)
            a = fmaf(sh1[k], W2[k * 3 + t], a);
        out[b * 3 + t] = a * BN_SCALE;
    }
}

// ---------------------------------------------------------------------------
extern "C" void kernel_launch(void* const* d_in, const int* in_sizes, int n_in,
                              void* d_out, int out_size, void* d_ws, size_t ws_size,
                              hipStream_t stream) {
    const int*   x1  = (const int*)d_in[0];
    const int*   x2  = (const int*)d_in[1];
    const float* E   = (const float*)d_in[2];
    const float* Wfw = (const float*)d_in[3];
    const float* bfw = (const float*)d_in[4];
    const float* Wbw = (const float*)d_in[5];
    const float* bbw = (const float*)d_in[6];
    const float* W1  = (const float*)d_in[7];
    const float* b1  = (const float*)d_in[8];
    const float* W2  = (const float*)d_in[9];
    const float* b2  = (const float*)d_in[10];
    float* out = (float*)d_out;

    // ws layout: P [50000*200] f32 (40 MB) | feat [1024*100] f32
    float* Pm   = (float*)d_ws;
    float* feat = Pm + (size_t)VOCAB * GATES;

    vocab_proj<<<(VOCAB + 31) / 32, 256, 0, stream>>>(E, Wfw, Pm);
    lstm_fw<<<BATCH, 64, 0, stream>>>(x1, x2, Pm, Wfw, bfw, feat);
    bw_mlp<<<BATCH, 256, 0, stream>>>(x2, E, Wbw, bbw, W1, b1, W2, b2, feat, out);
}

// Round 3
// 470.270 us; speedup vs baseline: 2.2307x; 2.2307x over previous
//
#include <hip/hip_runtime.h>
#include <hip/hip_bf16.h>

// Network: bidirectional LSTM (T=256, B=1024, E=300, H=50) + small MLP head.
// h_bw[0] needs only ONE backward step (zero init state); x@Wx hoisted into
// per-VOCAB precompute P = E @ W_fw[0:300,:] computed with split-bf16 MFMA.

#define VOCAB 50000
#define EMB   300
#define HID   50
#define GATES 200          // 4*H
#define BATCH 1024
#define TT    256          // 2*MAX_LEN
#define NPAD  208          // 13 * 16
#define KPAD  320          // 10 * 32
#define BN_SCALE 0.9995003746877732f   // 1/sqrt(1.001)

typedef short bf16x8 __attribute__((ext_vector_type(8)));
typedef float f32x4  __attribute__((ext_vector_type(4)));

__device__ __forceinline__ float sigm(float x) {
    return 1.0f / (1.0f + __expf(-x));
}
__device__ __forceinline__ float tanh_f(float x) {
    return 1.0f - 2.0f / (__expf(2.0f * x) + 1.0f);   // saturates correctly
}
__device__ __forceinline__ unsigned short f32_to_bf16(float x) {
    unsigned int u = __float_as_uint(x);
    u += 0x7fffu + ((u >> 16) & 1u);   // round-to-nearest-even (finite inputs)
    return (unsigned short)(u >> 16);
}
__device__ __forceinline__ float bf16_to_f32(unsigned short h) {
    return __uint_as_float(((unsigned int)h) << 16);
}

// ---------------------------------------------------------------------------
// K0: split Wx = W_fw[0:300,:] into bf16 hi/lo, TRANSPOSED + zero-padded to
// [NPAD][KPAD] so B-fragments are contiguous 16B loads. 66560 elems, tiny.
// ---------------------------------------------------------------------------
__global__ __launch_bounds__(256) void split_w(const float* __restrict__ Wfw,
                                               unsigned short* __restrict__ WhT,
                                               unsigned short* __restrict__ WlT) {
    const int idx = blockIdx.x * 256 + threadIdx.x;
    if (idx >= NPAD * KPAD) return;
    const int n = idx / KPAD;
    const int k = idx - n * KPAD;
    float v = (n < GATES && k < EMB) ? Wfw[k * GATES + n] : 0.0f;
    const unsigned short hb = f32_to_bf16(v);
    const unsigned short lb = f32_to_bf16(v - bf16_to_f32(hb));
    WhT[idx] = hb;
    WlT[idx] = lb;
}

// ---------------------------------------------------------------------------
// K1: P = E @ Wx via 16x16x32 bf16 MFMA, error-compensated split:
//     E*W ~= Eh*Wh + El*Wh + Eh*Wl  (f32 accumulate; dropped El*Wl ~ 1e-5).
// Block = 64 vocab rows, 4 waves; wave owns 16 rows x 208 cols (13 frags),
// K-loop 10 steps of 32 (E padded by guard, W padded in split_w).
// A-frag layout: row = lane&15, k = (lane>>4)*8 + j.
// B-frag layout: col = lane&15, k = (lane>>4)*8 + j (contiguous in WhT).
// C/D layout: col = lane&15, row = (lane>>4)*4 + reg   [measured m89/m91]
// ---------------------------------------------------------------------------
__global__ __launch_bounds__(256) void vocab_proj_mfma(const float* __restrict__ E,
                                                       const unsigned short* __restrict__ WhT,
                                                       const unsigned short* __restrict__ WlT,
                                                       float* __restrict__ P) {
    const int w  = threadIdx.x >> 6;
    const int l  = threadIdx.x & 63;
    const int lr = l & 15;        // row-in-tile (A) / col-in-frag (B, C)
    const int lg = l >> 4;        // k-group (A,B) / row-group (C)

    const int row    = blockIdx.x * 64 + w * 16 + lr;
    const int rclamp = (row < VOCAB) ? row : (VOCAB - 1);
    const float* Erow = E + (size_t)rclamp * EMB;

    f32x4 acc[13];
#pragma unroll
    for (int f = 0; f < 13; ++f) acc[f] = (f32x4){0.f, 0.f, 0.f, 0.f};

    for (int ks = 0; ks < 10; ++ks) {
        const int k0 = ks * 32 + lg * 8;
        float av[8];
        if (ks < 9) {
            const float4 a0 = *reinterpret_cast<const float4*>(Erow + k0);
            const float4 a1 = *reinterpret_cast<const float4*>(Erow + k0 + 4);
            av[0] = a0.x; av[1] = a0.y; av[2] = a0.z; av[3] = a0.w;
            av[4] = a1.x; av[5] = a1.y; av[6] = a1.z; av[7] = a1.w;
        } else {
#pragma unroll
            for (int j = 0; j < 8; ++j) {
                const int kk = k0 + j;
                av[j] = (kk < EMB) ? Erow[kk] : 0.0f;
            }
        }
        bf16x8 ah, al;
#pragma unroll
        for (int j = 0; j < 8; ++j) {
            const unsigned short hb = f32_to_bf16(av[j]);
            ah[j] = (short)hb;
            al[j] = (short)f32_to_bf16(av[j] - bf16_to_f32(hb));
        }

#pragma unroll
        for (int f = 0; f < 13; ++f) {
            const int n = f * 16 + lr;
            const size_t boff = (size_t)n * KPAD + k0;
            const bf16x8 bh = *reinterpret_cast<const bf16x8*>(WhT + boff);
            const bf16x8 bl = *reinterpret_cast<const bf16x8*>(WlT + boff);
            acc[f] = __builtin_amdgcn_mfma_f32_16x16x32_bf16(ah, bh, acc[f], 0, 0, 0);
            acc[f] = __builtin_amdgcn_mfma_f32_16x16x32_bf16(al, bh, acc[f], 0, 0, 0);
            acc[f] = __builtin_amdgcn_mfma_f32_16x16x32_bf16(ah, bl, acc[f], 0, 0, 0);
        }
    }

    const int orow0 = blockIdx.x * 64 + w * 16 + lg * 4;
#pragma unroll
    for (int f = 0; f < 13; ++f) {
        const int col = f * 16 + lr;
        if (col < GATES) {
#pragma unroll
            for (int r = 0; r < 4; ++r) {
                const int orow = orow0 + r;
                if (orow < VOCAB) P[(size_t)orow * GATES + col] = acc[f][r];
            }
        }
    }
}

// ---------------------------------------------------------------------------
// K2: forward LSTM. 2 waves per batch row: wave0 computes gates i,j; wave1
// computes f,o (100 weight VGPRs each -- no spill). Both waves redundantly
// keep c,h in lanes 0..49; h broadcast via readlane (VALU/SGPR, no DS).
// Per step: 1 float2 LDS write + 1 float2 read (parity double-buffer) and one
// raw s_barrier with lgkmcnt-only drain, so the P prefetch (issued one step
// ahead) stays in flight across the barrier.
// ---------------------------------------------------------------------------
__global__ __launch_bounds__(128) void lstm_fw(const int* __restrict__ x1,
                                               const int* __restrict__ x2,
                                               const float* __restrict__ P,
                                               const float* __restrict__ Wfw,
                                               const float* __restrict__ bfw,
                                               float* __restrict__ feat) {
    const int b = blockIdx.x;
    const int w = threadIdx.x >> 6;      // 0: gates i,j ; 1: gates f,o
    const int l = threadIdx.x & 63;
    const int u = (l < HID) ? l : (HID - 1);   // clamp for loads
    const bool act_lane = (l < HID);

    __shared__ int   stok[TT];
    __shared__ float ex[2][2][HID][2];   // [parity][wave][unit][{v0,v1}]

    stok[threadIdx.x]       = x1[b * 128 + threadIdx.x];
    stok[128 + threadIdx.x] = x2[b * 128 + threadIdx.x];

    const int cA = u + (w ? 100 : 0);    // i or f column
    const int cB = u + (w ? 150 : 50);   // o or j column
    float wA[HID], wB[HID];
#pragma unroll
    for (int k = 0; k < HID; ++k) {
        const float* rowp = Wfw + (size_t)(EMB + k) * GATES;
        wA[k] = rowp[cA];
        wB[k] = rowp[cB];
    }
    float bA = bfw[cA] + (w ? 1.0f : 0.0f);   // forget_bias folded into f
    float bB = bfw[cB];

    float c = 0.0f, h = 0.0f;
    __syncthreads();   // tokens ready (once)

    int tok = stok[0];
    float pA = P[(size_t)tok * GATES + cA];
    float pB = P[(size_t)tok * GATES + cB];
    int tokn = stok[1];

    for (int t = 0; t < TT; ++t) {
        float aA = pA + bA;
        float aB = pB + bB;

        // prefetch step t+1 (in flight across the barrier: no vmcnt drain)
        {
            const float* pr = P + (size_t)tokn * GATES;
            pA = pr[cA];
            pB = pr[cB];
        }
        const int t2 = (t + 2 < TT) ? (t + 2) : (TT - 1);
        tokn = stok[t2];

        // matvec: h broadcast via readlane -> SGPR operand in the FMA
#pragma unroll
        for (int k = 0; k < HID; ++k) {
            const float hk = __uint_as_float(
                __builtin_amdgcn_readlane(__float_as_uint(h), k));
            aA = fmaf(wA[k], hk, aA);
            aB = fmaf(wB[k], hk, aB);
        }

        // own activations: wave0 -> (sigm(i), tanh(j)); wave1 -> (sigm(f+1), sigm(o))
        const float e0 = sigm(aA);
        const float e1 = (w == 0) ? tanh_f(aB) : sigm(aB);
        if (act_lane)
            *reinterpret_cast<float2*>(&ex[t & 1][w][l][0]) = make_float2(e0, e1);

        asm volatile("s_waitcnt lgkmcnt(0)" ::: "memory");
        __builtin_amdgcn_s_barrier();

        const float2 o01 = *reinterpret_cast<const float2*>(&ex[t & 1][w ^ 1][u][0]);
        const float si = (w == 0) ? e0 : o01.x;
        const float tj = (w == 0) ? e1 : o01.y;
        const float sf = (w == 0) ? o01.x : e0;
        const float so = (w == 0) ? o01.y : e1;

        c = c * sf + si * tj;
        h = tanh_f(c) * so;
    }

    if (w == 0 && act_lane) feat[b * (2 * HID) + l] = h;
}

// ---------------------------------------------------------------------------
// K3: backward LSTM = ONE step (zero init state), fused with BN + MLP head.
// ---------------------------------------------------------------------------
__global__ __launch_bounds__(256) void bw_mlp(const int* __restrict__ x2,
                                              const float* __restrict__ E,
                                              const float* __restrict__ Wbw,
                                              const float* __restrict__ bbw,
                                              const float* __restrict__ W1,
                                              const float* __restrict__ b1,
                                              const float* __restrict__ W2,
                                              const float* __restrict__ b2,
                                              const float* __restrict__ featfw,
                                              float* __restrict__ out) {
    const int b = blockIdx.x;
    const int t = threadIdx.x;

    __shared__ __align__(16) float sx[EMB + 4];
    __shared__ float sf[2 * HID];
    __shared__ float sg[GATES];
    __shared__ float sh1[25];

    const int tok = x2[b * 128 + 127];   // xs[T-1] token
    for (int e = t; e < EMB; e += 256) sx[e] = E[(size_t)tok * EMB + e];
    if (t < HID) sf[t] = featfw[b * (2 * HID) + t];
    __syncthreads();

    if (t < GATES) {
        float g0 = bbw[t], g1 = 0.0f, g2 = 0.0f, g3 = 0.0f;
        for (int e = 0; e < EMB; e += 4) {
            g0 = fmaf(sx[e + 0], Wbw[(e + 0) * GATES + t], g0);
            g1 = fmaf(sx[e + 1], Wbw[(e + 1) * GATES + t], g1);
            g2 = fmaf(sx[e + 2], Wbw[(e + 2) * GATES + t], g2);
            g3 = fmaf(sx[e + 3], Wbw[(e + 3) * GATES + t], g3);
        }
        sg[t] = (g0 + g1) + (g2 + g3);
    }
    __syncthreads();

    if (t < HID) {
        const float c2 = sigm(sg[t]) * tanh_f(sg[t + HID]);
        sf[HID + t] = tanh_f(c2) * sigm(sg[t + 3 * HID]);
    }
    __syncthreads();

    if (t < 25) {
        float a = 0.0f;
#pragma unroll 4
        for (int k = 0; k < 2 * HID; ++k)
            a = fmaf(sf[k], W1[k * 25 + t], a);
        a = fmaf(a, BN_SCALE, b1[t]);
        sh1[t] = fmaxf(a, 0.0f);
    }
    __syncthreads();

    if (t < 3) {
        float a = b2[t];
#pragma unroll
        for (int k = 0; k < 25; ++k)
            a = fmaf(sh1[k], W2[k * 3 + t], a);
        out[b * 3 + t] = a * BN_SCALE;
    }
}

// ---------------------------------------------------------------------------
extern "C" void kernel_launch(void* const* d_in, const int* in_sizes, int n_in,
                              void* d_out, int out_size, void* d_ws, size_t ws_size,
                              hipStream_t stream) {
    const int*   x1  = (const int*)d_in[0];
    const int*   x2  = (const int*)d_in[1];
    const float* E   = (const float*)d_in[2];
    const float* Wfw = (const float*)d_in[3];
    const float* bfw = (const float*)d_in[4];
    const float* Wbw = (const float*)d_in[5];
    const float* bbw = (const float*)d_in[6];
    const float* W1  = (const float*)d_in[7];
    const float* b1  = (const float*)d_in[8];
    const float* W2  = (const float*)d_in[9];
    const float* b2  = (const float*)d_in[10];
    float* out = (float*)d_out;

    // ws layout: P [50000*200] f32 (40 MB) | feat [1024*100] f32 | WhT | WlT
    float* Pm   = (float*)d_ws;
    float* feat = Pm + (size_t)VOCAB * GATES;
    unsigned short* WhT = (unsigned short*)(feat + BATCH * 2 * HID);
    unsigned short* WlT = WhT + (size_t)NPAD * KPAD;

    split_w<<<(NPAD * KPAD + 255) / 256, 256, 0, stream>>>(Wfw, WhT, WlT);
    vocab_proj_mfma<<<(VOCAB + 63) / 64, 256, 0, stream>>>(E, WhT, WlT, Pm);
    lstm_fw<<<BATCH, 128, 0, stream>>>(x1, x2, Pm, Wfw, bfw, feat);
    bw_mlp<<<BATCH, 256, 0, stream>>>(x2, E, Wbw, bbw, W1, b1, W2, b2, feat, out);
}